// Round 1
// baseline (509.760 us; speedup 1.0000x reference)
//
#include <hip/hip_runtime.h>
#include <hip/hip_bf16.h>
#include <stdint.h>

// Problem constants (fixed by the reference)
#define N_ 16384
#define M_ 4096
#define D_ 256
#define O_ 256

// Workspace layout (bytes), total ~46.4 MB
#define WS_T    0          // float[N]      exp(sf+ba)     64 KB
#define WS_U    65536      // float[M]      exp(sc)        16 KB
#define WS_R    81920      // float[D]      colsum(Hc)      1 KB
#define WS_LSUM 98304      // float[N]      row denoms     64 KB
#define WS_WTP  163840     // ushort        Wt packed     128 KB
#define WS_BP1  294912     // ushort        u*Hc packed     2 MB
#define WS_BP2  2392064    // ushort        Hc packed       2 MB
#define WS_ABM  4489216    // u64[N*64]     adj bit-matrix  8 MB
#define WS_CP   12877824   // float[2*N*D]  split-K fp32   33.5 MB

typedef float  f32x4  __attribute__((ext_vector_type(4)));
typedef short  short8 __attribute__((ext_vector_type(8)));

// fp32 -> bf16 (RNE). Inputs are finite so no NaN handling.
__device__ __forceinline__ unsigned short f2bf(float f) {
  uint32_t u = __float_as_uint(f);
  u += 0x7FFFu + ((u >> 16) & 1u);
  return (unsigned short)(u >> 16);
}
// packed pair fp32 -> bf16
__device__ __forceinline__ uint32_t cvtpk(float a, float b) {
  __hip_bfloat162 h = __float22bfloat162_rn(float2{a, b});
  uint32_t u;
  __builtin_memcpy(&u, &h, 4);
  return u;
}

// ---------------------------------------------------------------------------
// Prep 1: per-row dot with weight vector, then exp(dot + bias).
__global__ __launch_bounds__(256) void rowdot_exp_kernel(
    const float* __restrict__ X, const float* __restrict__ w,
    const float* __restrict__ bias, float* __restrict__ outv) {
  int wv = threadIdx.x >> 6, lane = threadIdx.x & 63;
  int row = blockIdx.x * 4 + wv;
  const float4* x4 = (const float4*)(X + (size_t)row * D_);
  const float4* w4 = (const float4*)w;
  float4 xa = x4[lane], wa4 = w4[lane];
  float s = xa.x * wa4.x + xa.y * wa4.y + xa.z * wa4.z + xa.w * wa4.w;
#pragma unroll
  for (int off = 32; off > 0; off >>= 1) s += __shfl_xor(s, off);
  if (lane == 0) outv[row] = expf(s + (bias ? bias[0] : 0.0f));
}

// ---------------------------------------------------------------------------
// Prep 2: Hc [M,D] fp32 -> BP2 (Hc) and BP1 (u*Hc), fragment-major bf16,
// plus colsum(Hc) -> R.
// BP[((kg*16 + cg)*64 + lane)*8 + j] = bf16(val[kg*32+q*8+j][cg*16+m]), lane=q*16+m.
__global__ __launch_bounds__(256) void hc_pack_kernel(
    const float* __restrict__ Hc, const float* __restrict__ uv,
    unsigned short* __restrict__ BP1, unsigned short* __restrict__ BP2,
    float* __restrict__ R) {
  __shared__ float tile[64][65];
  __shared__ float red[4][64];
  __shared__ float u_tile[64];
  int bk = blockIdx.x >> 2;   // 64 tiles along M (k)
  int bc = blockIdx.x & 3;    // 4 tiles along D (col)
  int k0 = bk * 64, col0 = bc * 64;
  int t = threadIdx.x;
  int lane = t & 63, wv = t >> 6;
  int m = lane & 15, q = lane >> 4;
  if (t < 64) u_tile[t] = uv[k0 + t];
  float colsum = 0.0f;
#pragma unroll
  for (int i = 0; i < 16; ++i) {
    int e = t + 256 * i;
    int kk = e >> 6, cc = e & 63;
    float v = Hc[(size_t)(k0 + kk) * D_ + col0 + cc];
    tile[kk][cc] = v;
    colsum += v;
  }
  red[wv][t & 63] = colsum;
  __syncthreads();
  if (t < 64)
    atomicAdd(&R[col0 + t], red[0][t] + red[1][t] + red[2][t] + red[3][t]);
#pragma unroll
  for (int t8 = 0; t8 < 2; ++t8) {
    int tile_id = t8 * 4 + wv;
    int sub = tile_id >> 2, g = tile_id & 3;
    int kgg = bk * 2 + sub;
    int cgg = bc * 4 + g;
    short8 v1, v2;
#pragma unroll
    for (int j = 0; j < 8; ++j) {
      int kk = sub * 32 + q * 8 + j;
      float v = tile[kk][g * 16 + m];
      v2[j] = (short)f2bf(v);
      v1[j] = (short)f2bf(u_tile[kk] * v);
    }
    size_t off = ((size_t)(kgg * 16 + cgg) * 64 + lane) * 8;
    *(short8*)(BP1 + off) = v1;
    *(short8*)(BP2 + off) = v2;
  }
}

// ---------------------------------------------------------------------------
// Prep 3: Wt [O,D] fp32 -> WtP fragment-major bf16 (kg 0..7, cg 0..15).
__global__ __launch_bounds__(256) void wt_pack_kernel(
    const float* __restrict__ Wt, unsigned short* __restrict__ WtP) {
  int t = blockIdx.x * 256 + threadIdx.x;    // 0..8191
  int lane = t & 63, cg = (t >> 6) & 15, kg = t >> 10;
  int m = lane & 15, q = lane >> 4;
  const float* src = Wt + (size_t)(cg * 16 + m) * D_ + kg * 32 + q * 8;
  float4 w0 = *(const float4*)src, w1 = *(const float4*)(src + 4);
  short8 v8;
  v8[0] = (short)f2bf(w0.x); v8[1] = (short)f2bf(w0.y);
  v8[2] = (short)f2bf(w0.z); v8[3] = (short)f2bf(w0.w);
  v8[4] = (short)f2bf(w1.x); v8[5] = (short)f2bf(w1.y);
  v8[6] = (short)f2bf(w1.z); v8[7] = (short)f2bf(w1.w);
  *(short8*)(WtP + (size_t)t * 8) = v8;
}

// ---------------------------------------------------------------------------
// pack_bits v2 (unchanged, proven HBM-bound): row-contiguous adj stream,
// __ballot packs 64 k-contiguous bits; exact row denoms
// Lsum[r] = t_r*sum(adj*u) - sum(adj). Grid = 2048 x 256 thr.
__global__ __launch_bounds__(256) void pack_bits_kernel(
    const float* __restrict__ adj, const float* __restrict__ tv,
    const float* __restrict__ uv, unsigned long long* __restrict__ ABM,
    float* __restrict__ Lsum) {
  __shared__ float u_lds[M_];   // 16 KB
  int tid = threadIdx.x;
  int w = tid >> 6, lane = tid & 63;
  for (int i = tid; i < M_; i += 256) u_lds[i] = uv[i];
  __syncthreads();
  int r0 = (blockIdx.x * 4 + w) * 2;
  const float* arA = adj + (size_t)r0 * M_;
  const float* arB = arA + M_;
  float suA = 0.f, scA = 0.f, suB = 0.f, scB = 0.f;

  float a0 = arA[lane], a1 = arA[64 + lane], a2 = arA[128 + lane], a3 = arA[192 + lane];
  float b0 = arB[lane], b1 = arB[64 + lane], b2 = arB[128 + lane], b3 = arB[192 + lane];
#pragma unroll 1
  for (int i = 0; i < 16; ++i) {
    int k0 = i * 256;
    int k1 = (i + 1 < 16) ? k0 + 256 : 0;     // wrap: harmless reload
    float na0 = arA[k1 + lane],       na1 = arA[k1 + 64 + lane];
    float na2 = arA[k1 + 128 + lane], na3 = arA[k1 + 192 + lane];
    float nb0 = arB[k1 + lane],       nb1 = arB[k1 + 64 + lane];
    float nb2 = arB[k1 + 128 + lane], nb3 = arB[k1 + 192 + lane];

    unsigned long long wA0 = __ballot(a0 != 0.0f), wA1 = __ballot(a1 != 0.0f);
    unsigned long long wA2 = __ballot(a2 != 0.0f), wA3 = __ballot(a3 != 0.0f);
    unsigned long long wB0 = __ballot(b0 != 0.0f), wB1 = __ballot(b1 != 0.0f);
    unsigned long long wB2 = __ballot(b2 != 0.0f), wB3 = __ballot(b3 != 0.0f);
    suA = fmaf(a0, u_lds[k0 + lane], suA);
    suA = fmaf(a1, u_lds[k0 + 64 + lane], suA);
    suA = fmaf(a2, u_lds[k0 + 128 + lane], suA);
    suA = fmaf(a3, u_lds[k0 + 192 + lane], suA);
    scA += (a0 + a1) + (a2 + a3);
    suB = fmaf(b0, u_lds[k0 + lane], suB);
    suB = fmaf(b1, u_lds[k0 + 64 + lane], suB);
    suB = fmaf(b2, u_lds[k0 + 128 + lane], suB);
    suB = fmaf(b3, u_lds[k0 + 192 + lane], suB);
    scB += (b0 + b1) + (b2 + b3);
    if (lane < 8) {
      int sel = lane & 3;
      unsigned long long vA = sel == 0 ? wA0 : sel == 1 ? wA1 : sel == 2 ? wA2 : wA3;
      unsigned long long vB = sel == 0 ? wB0 : sel == 1 ? wB1 : sel == 2 ? wB2 : wB3;
      int r = (lane < 4) ? r0 : r0 + 1;
      ABM[(size_t)r * 64 + i * 4 + sel] = (lane < 4) ? vA : vB;
    }
    a0 = na0; a1 = na1; a2 = na2; a3 = na3;
    b0 = nb0; b1 = nb1; b2 = nb2; b3 = nb3;
  }
#pragma unroll
  for (int off = 32; off > 0; off >>= 1) {
    suA += __shfl_xor(suA, off); scA += __shfl_xor(scA, off);
    suB += __shfl_xor(suB, off); scB += __shfl_xor(scB, off);
  }
  if (lane == 0) {
    Lsum[r0] = tv[r0] * suA - scA;
    Lsum[r0 + 1] = tv[r0 + 1] * suB - scB;
  }
}

// ---------------------------------------------------------------------------
// Build the A1/A2 bf16 MFMA fragments for one row-tile from 8 adj bits:
//   A1 slot j = bit_j ? bf16(t) : 0      (feeds B1 = u*Hc)
//   A2 slot j = bit_j ? -1.0   : 0      (feeds B2 = Hc)
// Mask-only: no fma/cvt in the K-loop (t packed outside). 0x0000 mask is
// exact +0.0 (R7-proven trick).
__device__ __forceinline__ void frag01(uint32_t bits, uint32_t tpk,
                                       short8* a1, short8* a2) {
  union { short8 s; uint32_t u[4]; } r1, r2;
#pragma unroll
  for (int p = 0; p < 4; ++p) {
    uint32_t mlo = 0u - ((bits >> (2 * p)) & 1u);      // 0 or ~0
    uint32_t mhi = 0u - ((bits >> (2 * p + 1)) & 1u);
    uint32_t msk = (mlo & 0x0000FFFFu) | (mhi & 0xFFFF0000u);
    r1.u[p] = tpk & msk;
    r2.u[p] = 0xBF80BF80u & msk;                       // -1.0 bf16 pair
  }
  *a1 = r1.s; *a2 = r2.s;
}

// ---------------------------------------------------------------------------
// GEMM v3: K-doubled two-B single-accumulator form.
//   acc = sum_k [ (t*adj) x (u.Hc)  +  (-adj) x Hc ]  =  t*G1 - G2
// 64-row x 256-col blocks, 1024 thr = 16 waves (8 colq x 2 ksub).
// Each wave: 4 row-tiles x 2 col-groups x 2048-K half (64 ksteps).
// Registers: acc 32 + B 16 + frag 8 transient + tpk 4 + misc ~ 90 VGPR —
// fits the 128 cap of __launch_bounds__(1024,4) with no scratch (the v2
// kernel's ~142 live VGPRs spilled in-loop).
// B (both matrices) read exactly once per block. Bits from padded LDS.
// Split-K=2 partials stored fp32. Grid = N/64 = 256 -> 1 block/CU.
__global__ __launch_bounds__(1024, 4) void gemm_kernel(
    const unsigned int* __restrict__ ABM32, const unsigned short* __restrict__ BP1,
    const unsigned short* __restrict__ BP2, const float* __restrict__ tv,
    float* __restrict__ Cp) {
  __shared__ unsigned int bt2[64][129];   // 33 KB, pad -> bank=(row+word)%32
  int tid = threadIdx.x;
  int w = tid >> 6, lane = tid & 63;
  int q = lane >> 4, m = lane & 15;
  int colq = w & 7, ksub = w >> 3;
  int i0 = blockIdx.x * 64;

  float t0 = tv[i0 + m],      t1 = tv[i0 + 16 + m];
  float t2 = tv[i0 + 32 + m], t3 = tv[i0 + 48 + m];
  uint32_t tp0 = cvtpk(t0, t0), tp1 = cvtpk(t1, t1);
  uint32_t tp2 = cvtpk(t2, t2), tp3 = cvtpk(t3, t3);

  for (int p = tid; p < 8192; p += 1024) {
    int row = p >> 7, word = p & 127;     // coalesced global; conflict-free LDS
    bt2[row][word] = ABM32[(size_t)(i0 + row) * 128 + word];
  }

  f32x4 acc[4][2];
#pragma unroll
  for (int s = 0; s < 4; ++s)
#pragma unroll
    for (int n = 0; n < 2; ++n) acc[s][n] = (f32x4){0.f, 0.f, 0.f, 0.f};

  int kg0 = ksub * 64;
  const unsigned short* b1p = BP1 + (size_t)(kg0 * 16 + colq * 2) * 512 + (size_t)lane * 8;
  const unsigned short* b2p = BP2 + (size_t)(kg0 * 16 + colq * 2) * 512 + (size_t)lane * 8;
  int sh = q * 8;

  __syncthreads();  // bits ready (only barrier)

#pragma unroll 2
  for (int it = 0; it < 64; ++it) {
    int kg = kg0 + it;
    // B loads issued first; L2-resident, latency covered by mask build
    const unsigned short* b1k = b1p + (size_t)it * 8192;
    const unsigned short* b2k = b2p + (size_t)it * 8192;
    short8 B1a = *(const short8*)(b1k);
    short8 B1b = *(const short8*)(b1k + 512);
    short8 B2a = *(const short8*)(b2k);
    short8 B2b = *(const short8*)(b2k + 512);

    uint32_t w0 = (bt2[m][kg] >> sh) & 0xffu;
    uint32_t w1 = (bt2[16 + m][kg] >> sh) & 0xffu;
    uint32_t w2 = (bt2[32 + m][kg] >> sh) & 0xffu;
    uint32_t w3 = (bt2[48 + m][kg] >> sh) & 0xffu;

    short8 a1, a2;
    frag01(w0, tp0, &a1, &a2);
    acc[0][0] = __builtin_amdgcn_mfma_f32_16x16x32_bf16(a1, B1a, acc[0][0], 0, 0, 0);
    acc[0][0] = __builtin_amdgcn_mfma_f32_16x16x32_bf16(a2, B2a, acc[0][0], 0, 0, 0);
    acc[0][1] = __builtin_amdgcn_mfma_f32_16x16x32_bf16(a1, B1b, acc[0][1], 0, 0, 0);
    acc[0][1] = __builtin_amdgcn_mfma_f32_16x16x32_bf16(a2, B2b, acc[0][1], 0, 0, 0);
    frag01(w1, tp1, &a1, &a2);
    acc[1][0] = __builtin_amdgcn_mfma_f32_16x16x32_bf16(a1, B1a, acc[1][0], 0, 0, 0);
    acc[1][0] = __builtin_amdgcn_mfma_f32_16x16x32_bf16(a2, B2a, acc[1][0], 0, 0, 0);
    acc[1][1] = __builtin_amdgcn_mfma_f32_16x16x32_bf16(a1, B1b, acc[1][1], 0, 0, 0);
    acc[1][1] = __builtin_amdgcn_mfma_f32_16x16x32_bf16(a2, B2b, acc[1][1], 0, 0, 0);
    frag01(w2, tp2, &a1, &a2);
    acc[2][0] = __builtin_amdgcn_mfma_f32_16x16x32_bf16(a1, B1a, acc[2][0], 0, 0, 0);
    acc[2][0] = __builtin_amdgcn_mfma_f32_16x16x32_bf16(a2, B2a, acc[2][0], 0, 0, 0);
    acc[2][1] = __builtin_amdgcn_mfma_f32_16x16x32_bf16(a1, B1b, acc[2][1], 0, 0, 0);
    acc[2][1] = __builtin_amdgcn_mfma_f32_16x16x32_bf16(a2, B2b, acc[2][1], 0, 0, 0);
    frag01(w3, tp3, &a1, &a2);
    acc[3][0] = __builtin_amdgcn_mfma_f32_16x16x32_bf16(a1, B1a, acc[3][0], 0, 0, 0);
    acc[3][0] = __builtin_amdgcn_mfma_f32_16x16x32_bf16(a2, B2a, acc[3][0], 0, 0, 0);
    acc[3][1] = __builtin_amdgcn_mfma_f32_16x16x32_bf16(a1, B1b, acc[3][1], 0, 0, 0);
    acc[3][1] = __builtin_amdgcn_mfma_f32_16x16x32_bf16(a2, B2b, acc[3][1], 0, 0, 0);
  }

  // split-K partial (already t*G1 - G2), fp32 plane ksub
  float* cpb = Cp + (size_t)ksub * N_ * D_;
#pragma unroll
  for (int s = 0; s < 4; ++s)
#pragma unroll
    for (int n = 0; n < 2; ++n) {
      int col = (colq * 2 + n) * 16 + m;
#pragma unroll
      for (int r = 0; r < 4; ++r) {
        size_t row = (size_t)i0 + s * 16 + q * 4 + r;  // C/D: row=(lane>>4)*4+reg
        cpb[row * D_ + col] = acc[s][n][r];
      }
    }
}

// ---------------------------------------------------------------------------
// Epilogue: attn = (Cp0 + Cp1 + R)/(Lsum + M) + Hf -> LDS bf16 -> relu(attn@Wt^T+bt)
__global__ __launch_bounds__(256, 4) void epilogue_kernel(
    const float* __restrict__ Cp, const float* __restrict__ Lsum,
    const float* __restrict__ Rv, const float* __restrict__ Hf,
    const unsigned short* __restrict__ WtP, const float* __restrict__ bt,
    float* __restrict__ out) {
  __shared__ alignas(16) unsigned short attn[32][264];  // +8 pad
  int tid = threadIdx.x;
  int w = tid >> 6, lane = tid & 63;
  int rtile = w & 1, chalf = w >> 1;
  int q = lane >> 4, m = lane & 15;
  int i0 = blockIdx.x * 32;

  float4 rv = *(const float4*)(Rv + lane * 4);
#pragma unroll
  for (int rr = 0; rr < 8; ++rr) {
    int r = w * 8 + rr;                       // wave w owns rows w*8..w*8+7
    size_t row = (size_t)i0 + r;
    float invL = 1.0f / (Lsum[row] + (float)M_);
    float4 c0 = *(const float4*)(Cp + row * D_ + lane * 4);
    float4 c1 = *(const float4*)(Cp + ((size_t)N_ + row) * D_ + lane * 4);
    float4 hv = *(const float4*)(Hf + row * D_ + lane * 4);
    attn[r][lane * 4 + 0] = f2bf(fmaf(c0.x + c1.x + rv.x, invL, hv.x));
    attn[r][lane * 4 + 1] = f2bf(fmaf(c0.y + c1.y + rv.y, invL, hv.y));
    attn[r][lane * 4 + 2] = f2bf(fmaf(c0.z + c1.z + rv.z, invL, hv.z));
    attn[r][lane * 4 + 3] = f2bf(fmaf(c0.w + c1.w + rv.w, invL, hv.w));
  }
  __syncthreads();

  f32x4 facc[8];
#pragma unroll
  for (int n = 0; n < 8; ++n) facc[n] = (f32x4){0.f, 0.f, 0.f, 0.f};
  const unsigned short* wwave = WtP + (size_t)chalf * 4096 + (size_t)lane * 8;
#pragma unroll
  for (int kf = 0; kf < 8; ++kf) {
    short8 af = *(const short8*)&attn[rtile * 16 + m][kf * 32 + q * 8];
#pragma unroll
    for (int n = 0; n < 8; ++n) {
      short8 bf = *(const short8*)(wwave + ((size_t)kf * 16 + n) * 512);
      facc[n] = __builtin_amdgcn_mfma_f32_16x16x32_bf16(af, bf, facc[n], 0, 0, 0);
    }
  }
#pragma unroll
  for (int n = 0; n < 8; ++n) {
    int col = chalf * 128 + n * 16 + m;
    float b = bt[col];
#pragma unroll
    for (int r = 0; r < 4; ++r) {
      size_t row = (size_t)i0 + rtile * 16 + q * 4 + r;
      out[row * O_ + col] = fmaxf(facc[n][r] + b, 0.0f);
    }
  }
}

// ---------------------------------------------------------------------------
extern "C" void kernel_launch(void* const* d_in, const int* in_sizes, int n_in,
                              void* d_out, int out_size, void* d_ws, size_t ws_size,
                              hipStream_t stream) {
  const float* Hf  = (const float*)d_in[0];  // [N,D]
  const float* Hc  = (const float*)d_in[1];  // [M,D]
  const float* adj = (const float*)d_in[2];  // [N,M]
  const float* wa  = (const float*)d_in[3];  // [2D]
  const float* ba  = (const float*)d_in[4];  // [1]
  const float* Wt  = (const float*)d_in[5];  // [O,D]
  const float* bt  = (const float*)d_in[6];  // [O]
  float* out = (float*)d_out;

  char* ws = (char*)d_ws;
  float* tv   = (float*)(ws + WS_T);
  float* uv   = (float*)(ws + WS_U);
  float* Rv   = (float*)(ws + WS_R);
  float* Lsum = (float*)(ws + WS_LSUM);
  unsigned short* WtP = (unsigned short*)(ws + WS_WTP);
  unsigned short* BP1 = (unsigned short*)(ws + WS_BP1);
  unsigned short* BP2 = (unsigned short*)(ws + WS_BP2);
  unsigned long long* ABM = (unsigned long long*)(ws + WS_ABM);
  float* Cp = (float*)(ws + WS_CP);

  hipMemsetAsync(Rv, 0, D_ * sizeof(float), stream);  // atomic target

  rowdot_exp_kernel<<<N_ / 4, 256, 0, stream>>>(Hf, wa, ba, tv);           // t = exp(sf+ba)
  rowdot_exp_kernel<<<M_ / 4, 256, 0, stream>>>(Hc, wa + D_, nullptr, uv); // u = exp(sc)
  hc_pack_kernel<<<256, 256, 0, stream>>>(Hc, uv, BP1, BP2, Rv);
  wt_pack_kernel<<<32, 256, 0, stream>>>(Wt, WtP);

  pack_bits_kernel<<<2048, 256, 0, stream>>>(adj, tv, uv, ABM, Lsum);
  gemm_kernel<<<N_ / 64, 1024, 0, stream>>>((const unsigned int*)ABM, BP1, BP2, tv, Cp);
  epilogue_kernel<<<N_ / 32, 256, 0, stream>>>(Cp, Lsum, Rv, Hf, WtP, bt, out);
}

// Round 2
// 470.598 us; speedup vs baseline: 1.0832x; 1.0832x over previous
//
#include <hip/hip_runtime.h>
#include <hip/hip_bf16.h>
#include <stdint.h>

// Problem constants (fixed by the reference)
#define N_ 16384
#define M_ 4096
#define D_ 256
#define O_ 256

// Workspace layout (bytes), total ~10.4 MB
#define WS_T    0          // float[N]      exp(sf+ba)     64 KB
#define WS_U    65536      // float[M]      exp(sc)        16 KB
#define WS_R    81920      // float[D]      colsum(Hc)      1 KB
#define WS_LSUM 98304      // float[N]      row denoms     64 KB
#define WS_WTP  163840     // ushort        Wt packed     128 KB
#define WS_BP   294912     // ushort        Hc packed       2 MB
#define WS_ABM  2392064    // u64[N*64]     adj bit-matrix  8 MB

typedef float  f32x4  __attribute__((ext_vector_type(4)));
typedef short  short8 __attribute__((ext_vector_type(8)));

// fp32 -> bf16 (RNE). Inputs are finite so no NaN handling.
__device__ __forceinline__ unsigned short f2bf(float f) {
  uint32_t u = __float_as_uint(f);
  u += 0x7FFFu + ((u >> 16) & 1u);
  return (unsigned short)(u >> 16);
}
// packed pair fp32 -> bf16
__device__ __forceinline__ uint32_t cvtpk(float a, float b) {
  __hip_bfloat162 h = __float22bfloat162_rn(float2{a, b});
  uint32_t u;
  __builtin_memcpy(&u, &h, 4);
  return u;
}

// ---------------------------------------------------------------------------
// Merged prep: blocks [0,4096) rowdot(Hf)->tv, [4096,5120) rowdot(Hc)->uv,
// [5120,5376) hc_pack (BP + colsum->Rv atomics), [5376,5408) wt_pack.
// All four are independent; merged to cut dispatch gaps.
__global__ __launch_bounds__(256) void prep_kernel(
    const float* __restrict__ Hf, const float* __restrict__ Hc,
    const float* __restrict__ wa, const float* __restrict__ ba,
    const float* __restrict__ Wt, float* __restrict__ tv,
    float* __restrict__ uv, unsigned short* __restrict__ BP,
    unsigned short* __restrict__ WtP, float* __restrict__ Rv) {
  __shared__ float tile[64][65];
  __shared__ float red[4][64];
  int b = blockIdx.x;
  int t = threadIdx.x;
  if (b < 5120) {
    // ---- rowdot_exp: per-row dot with weight half, then exp(dot + bias)
    int wv = t >> 6, lane = t & 63;
    const float* X; const float* w; const float* bias; float* outv; int row;
    if (b < 4096) { X = Hf; w = wa;      bias = ba;      outv = tv; row = b * 4 + wv; }
    else          { X = Hc; w = wa + D_; bias = nullptr; outv = uv; row = (b - 4096) * 4 + wv; }
    const float4* x4 = (const float4*)(X + (size_t)row * D_);
    const float4* w4 = (const float4*)w;
    float4 xa = x4[lane], wa4 = w4[lane];
    float s = xa.x * wa4.x + xa.y * wa4.y + xa.z * wa4.z + xa.w * wa4.w;
#pragma unroll
    for (int off = 32; off > 0; off >>= 1) s += __shfl_xor(s, off);
    if (lane == 0) outv[row] = expf(s + (bias ? bias[0] : 0.0f));
  } else if (b < 5376) {
    // ---- hc_pack: Hc [M,D] fp32 -> BP fragment-major bf16 + colsum.
    // BP[((kg*16+cg)*64+lane)*8+j] = bf16(Hc[kg*32+q*8+j][cg*16+m]), lane=q*16+m.
    int bb = b - 5120;
    int bk = bb >> 2;   // 64 tiles along M (k)
    int bc = bb & 3;    // 4 tiles along D (col)
    int k0 = bk * 64, col0 = bc * 64;
    int lane = t & 63, wv = t >> 6;
    int m = lane & 15, q = lane >> 4;
    float colsum = 0.0f;
#pragma unroll
    for (int i = 0; i < 16; ++i) {
      int e = t + 256 * i;
      int kk = e >> 6, cc = e & 63;
      float v = Hc[(size_t)(k0 + kk) * D_ + col0 + cc];
      tile[kk][cc] = v;
      colsum += v;
    }
    red[wv][t & 63] = colsum;
    __syncthreads();
    if (t < 64)
      atomicAdd(&Rv[col0 + t], red[0][t] + red[1][t] + red[2][t] + red[3][t]);
#pragma unroll
    for (int t8 = 0; t8 < 2; ++t8) {
      int tile_id = t8 * 4 + wv;
      int sub = tile_id >> 2, g = tile_id & 3;
      int kgg = bk * 2 + sub;
      int cgg = bc * 4 + g;
      short8 v8;
#pragma unroll
      for (int j = 0; j < 8; ++j)
        v8[j] = (short)f2bf(tile[sub * 32 + q * 8 + j][g * 16 + m]);
      *(short8*)(BP + ((size_t)(kgg * 16 + cgg) * 64 + lane) * 8) = v8;
    }
  } else {
    // ---- wt_pack: Wt [O,D] fp32 -> WtP fragment-major bf16
    int tt = (b - 5376) * 256 + t;    // 0..8191
    int lane = tt & 63, cg = (tt >> 6) & 15, kg = tt >> 10;
    int m = lane & 15, q = lane >> 4;
    const float* src = Wt + (size_t)(cg * 16 + m) * D_ + kg * 32 + q * 8;
    float4 w0 = *(const float4*)src, w1 = *(const float4*)(src + 4);
    short8 v8;
    v8[0] = (short)f2bf(w0.x); v8[1] = (short)f2bf(w0.y);
    v8[2] = (short)f2bf(w0.z); v8[3] = (short)f2bf(w0.w);
    v8[4] = (short)f2bf(w1.x); v8[5] = (short)f2bf(w1.y);
    v8[6] = (short)f2bf(w1.z); v8[7] = (short)f2bf(w1.w);
    *(short8*)(WtP + (size_t)tt * 8) = v8;
  }
}

// ---------------------------------------------------------------------------
// pack_bits v2 (unchanged, proven HBM-bound): row-contiguous adj stream,
// __ballot packs 64 k-contiguous bits; exact row denoms
// Lsum[r] = t_r*sum(adj*u) - sum(adj). Grid = 2048 x 256 thr.
__global__ __launch_bounds__(256) void pack_bits_kernel(
    const float* __restrict__ adj, const float* __restrict__ tv,
    const float* __restrict__ uv, unsigned long long* __restrict__ ABM,
    float* __restrict__ Lsum) {
  __shared__ float u_lds[M_];   // 16 KB
  int tid = threadIdx.x;
  int w = tid >> 6, lane = tid & 63;
  for (int i = tid; i < M_; i += 256) u_lds[i] = uv[i];
  __syncthreads();
  int r0 = (blockIdx.x * 4 + w) * 2;
  const float* arA = adj + (size_t)r0 * M_;
  const float* arB = arA + M_;
  float suA = 0.f, scA = 0.f, suB = 0.f, scB = 0.f;

  float a0 = arA[lane], a1 = arA[64 + lane], a2 = arA[128 + lane], a3 = arA[192 + lane];
  float b0 = arB[lane], b1 = arB[64 + lane], b2 = arB[128 + lane], b3 = arB[192 + lane];
#pragma unroll 1
  for (int i = 0; i < 16; ++i) {
    int k0 = i * 256;
    int k1 = (i + 1 < 16) ? k0 + 256 : 0;     // wrap: harmless reload
    float na0 = arA[k1 + lane],       na1 = arA[k1 + 64 + lane];
    float na2 = arA[k1 + 128 + lane], na3 = arA[k1 + 192 + lane];
    float nb0 = arB[k1 + lane],       nb1 = arB[k1 + 64 + lane];
    float nb2 = arB[k1 + 128 + lane], nb3 = arB[k1 + 192 + lane];

    unsigned long long wA0 = __ballot(a0 != 0.0f), wA1 = __ballot(a1 != 0.0f);
    unsigned long long wA2 = __ballot(a2 != 0.0f), wA3 = __ballot(a3 != 0.0f);
    unsigned long long wB0 = __ballot(b0 != 0.0f), wB1 = __ballot(b1 != 0.0f);
    unsigned long long wB2 = __ballot(b2 != 0.0f), wB3 = __ballot(b3 != 0.0f);
    suA = fmaf(a0, u_lds[k0 + lane], suA);
    suA = fmaf(a1, u_lds[k0 + 64 + lane], suA);
    suA = fmaf(a2, u_lds[k0 + 128 + lane], suA);
    suA = fmaf(a3, u_lds[k0 + 192 + lane], suA);
    scA += (a0 + a1) + (a2 + a3);
    suB = fmaf(b0, u_lds[k0 + lane], suB);
    suB = fmaf(b1, u_lds[k0 + 64 + lane], suB);
    suB = fmaf(b2, u_lds[k0 + 128 + lane], suB);
    suB = fmaf(b3, u_lds[k0 + 192 + lane], suB);
    scB += (b0 + b1) + (b2 + b3);
    if (lane < 8) {
      int sel = lane & 3;
      unsigned long long vA = sel == 0 ? wA0 : sel == 1 ? wA1 : sel == 2 ? wA2 : wA3;
      unsigned long long vB = sel == 0 ? wB0 : sel == 1 ? wB1 : sel == 2 ? wB2 : wB3;
      int r = (lane < 4) ? r0 : r0 + 1;
      ABM[(size_t)r * 64 + i * 4 + sel] = (lane < 4) ? vA : vB;
    }
    a0 = na0; a1 = na1; a2 = na2; a3 = na3;
    b0 = nb0; b1 = nb1; b2 = nb2; b3 = nb3;
  }
#pragma unroll
  for (int off = 32; off > 0; off >>= 1) {
    suA += __shfl_xor(suA, off); scA += __shfl_xor(scA, off);
    suB += __shfl_xor(suB, off); scB += __shfl_xor(scB, off);
  }
  if (lane == 0) {
    Lsum[r0] = tv[r0] * suA - scA;
    Lsum[r0 + 1] = tv[r0 + 1] * suB - scB;
  }
}

// ---------------------------------------------------------------------------
// Build a bf16 MFMA A-fragment from 8 adj bits: slot j = bit_j ? (t*u_j - 1) : 0.
// Masking the packed bf16 pair with 0x0000 yields exact +0.0. (R7-proven.)
__device__ __forceinline__ short8 frag_bits(uint32_t bits, float t,
                                            float4 u0, float4 u1) {
  float c[8];
  c[0] = fmaf(t, u0.x, -1.0f); c[1] = fmaf(t, u0.y, -1.0f);
  c[2] = fmaf(t, u0.z, -1.0f); c[3] = fmaf(t, u0.w, -1.0f);
  c[4] = fmaf(t, u1.x, -1.0f); c[5] = fmaf(t, u1.y, -1.0f);
  c[6] = fmaf(t, u1.z, -1.0f); c[7] = fmaf(t, u1.w, -1.0f);
  union { short8 s; uint32_t u[4]; } r;
#pragma unroll
  for (int p = 0; p < 4; ++p) {
    uint32_t mlo = 0u - ((bits >> (2 * p)) & 1u);      // 0 or ~0
    uint32_t mhi = 0u - ((bits >> (2 * p + 1)) & 1u);
    r.u[p] = cvtpk(c[2 * p], c[2 * p + 1]) &
             ((mlo & 0x0000FFFFu) | (mhi & 0xFFFF0000u));
  }
  return r.s;
}

// ---------------------------------------------------------------------------
// Mega kernel: round-0 masked GEMM (known-good body) + fused epilogue.
// Phase 1 (K-loop): 64-row x 256-col block, 1024 thr = 16 waves
//   (4 colq x 4 ksub); each wave 4 row-tiles x 4 col-groups x 1024-K quarter.
//   Bits in padded LDS; B from prepacked BP with depth-1 register prefetch;
//   barrier-free K loop. Identical to the 488-us round-0 gemm.
// Phase 2: sequential ksub-plane reduction into fp32 LDS Cred[64][256]
//   (exact, replaces the bf16 Cp HBM round-trip: -67 MB HBM).
// Phase 3: attn = (Cred+R)/(Lsum+M) + Hf -> bf16 LDS (aliased over the dead
//   bit-table), then second GEMM attn @ Wt^T + bt, ReLU -> out.
// LDS: bt2 33 KB | u 16 KB | Cred 64 KB = 115 KB -> 1 block/CU (grid=256).
__global__ __launch_bounds__(1024, 4) void mega_kernel(
    const unsigned int* __restrict__ ABM32, const unsigned short* __restrict__ BP,
    const float* __restrict__ tv, const float* __restrict__ uv,
    const float* __restrict__ Lsum, const float* __restrict__ Rv,
    const float* __restrict__ Hf, const unsigned short* __restrict__ WtP,
    const float* __restrict__ bt, float* __restrict__ out) {
  __shared__ __align__(16) char smem[114944];
  unsigned int (*bt2)[129] = (unsigned int (*)[129])(smem);           // 33024 B
  float* u_lds = (float*)(smem + 33024);                              // 16384 B
  float (*Cred)[256] = (float (*)[256])(smem + 49408);                // 65536 B
  unsigned short (*attn)[264] = (unsigned short (*)[264])(smem);      // 33792 B (aliases bt2+u, both dead by then)

  int tid = threadIdx.x;
  int w = tid >> 6, lane = tid & 63;
  int q = lane >> 4, m = lane & 15;
  int colq = w >> 2, ksub = w & 3;
  int i0 = blockIdx.x * 64;

  // B base + first-kstep prefetch issued BEFORE the barrier (no LDS dep)
  const unsigned short* bbase = BP + (size_t)(colq * 4) * 512 + (size_t)lane * 8;
  int kg0 = ksub * 32;
  short8 curB[4];
#pragma unroll
  for (int n = 0; n < 4; ++n)
    curB[n] = *(const short8*)(bbase + ((size_t)kg0 * 16 + n) * 512);
  float t0 = tv[i0 + m], t1 = tv[i0 + 16 + m];
  float t2 = tv[i0 + 32 + m], t3 = tv[i0 + 48 + m];

  for (int i = tid; i < M_; i += 1024) u_lds[i] = uv[i];
  for (int p = tid; p < 8192; p += 1024) {
    int row = p >> 7, word = p & 127;     // coalesced global; conflict-free LDS
    bt2[row][word] = ABM32[(size_t)(i0 + row) * 128 + word];
  }

  f32x4 acc[4][4];
#pragma unroll
  for (int s = 0; s < 4; ++s)
#pragma unroll
    for (int n = 0; n < 4; ++n) acc[s][n] = (f32x4){0.f, 0.f, 0.f, 0.f};

  __syncthreads();  // bits + u ready

  for (int it = 0; it < 32; ++it) {
    int kg = kg0 + it;
    int kn = (it + 1 < 32) ? kg + 1 : kg0;   // wrap: harmless reload
    short8 nB[4];
#pragma unroll
    for (int n = 0; n < 4; ++n)
      nB[n] = *(const short8*)(bbase + ((size_t)kn * 16 + n) * 512);

    float4 u0 = *(const float4*)&u_lds[kg * 32 + q * 8];
    float4 u1 = *(const float4*)&u_lds[kg * 32 + q * 8 + 4];
    uint32_t b0 = bt2[m][kg],      b1 = bt2[16 + m][kg];
    uint32_t b2 = bt2[32 + m][kg], b3 = bt2[48 + m][kg];
    int sh = q * 8;
    short8 af0 = frag_bits((b0 >> sh) & 0xffu, t0, u0, u1);
    short8 af1 = frag_bits((b1 >> sh) & 0xffu, t1, u0, u1);
    short8 af2 = frag_bits((b2 >> sh) & 0xffu, t2, u0, u1);
    short8 af3 = frag_bits((b3 >> sh) & 0xffu, t3, u0, u1);
#pragma unroll
    for (int n = 0; n < 4; ++n) {
      acc[0][n] = __builtin_amdgcn_mfma_f32_16x16x32_bf16(af0, curB[n], acc[0][n], 0, 0, 0);
      acc[1][n] = __builtin_amdgcn_mfma_f32_16x16x32_bf16(af1, curB[n], acc[1][n], 0, 0, 0);
      acc[2][n] = __builtin_amdgcn_mfma_f32_16x16x32_bf16(af2, curB[n], acc[2][n], 0, 0, 0);
      acc[3][n] = __builtin_amdgcn_mfma_f32_16x16x32_bf16(af3, curB[n], acc[3][n], 0, 0, 0);
    }
#pragma unroll
    for (int n = 0; n < 4; ++n) curB[n] = nB[n];
  }

  // ---- Phase 2: sequential ksub-plane reduction into fp32 Cred (exact)
#pragma unroll
  for (int s4 = 0; s4 < 4; ++s4) {
    if (ksub == s4) {
#pragma unroll
      for (int s = 0; s < 4; ++s)
#pragma unroll
        for (int n = 0; n < 4; ++n) {
          int col = colq * 64 + n * 16 + m;
#pragma unroll
          for (int r = 0; r < 4; ++r) {
            int rl = s * 16 + q * 4 + r;     // C/D: row=(lane>>4)*4+reg
            if (s4 == 0) Cred[rl][col] = acc[s][n][r];
            else         Cred[rl][col] += acc[s][n][r];
          }
        }
    }
    __syncthreads();
  }

  // ---- Phase 3a: attn = (Cred + R)/(Lsum + M) + Hf -> bf16 LDS
  {
    int row = tid >> 4;                 // 0..63, 16 threads per row
    int c0 = (tid & 15) * 16;           // 16 consecutive cols per thread
    size_t grow = (size_t)i0 + row;
    float invL = 1.0f / (Lsum[grow] + (float)M_);
    const float* hfp = Hf + grow * D_ + c0;
    const float* rvp = Rv + c0;
    const float* crp = &Cred[row][c0];
#pragma unroll
    for (int g = 0; g < 4; ++g) {
      float4 cv = *(const float4*)(crp + g * 4);
      float4 rv = *(const float4*)(rvp + g * 4);
      float4 hv = *(const float4*)(hfp + g * 4);
      float v0 = fmaf(cv.x + rv.x, invL, hv.x);
      float v1 = fmaf(cv.y + rv.y, invL, hv.y);
      float v2 = fmaf(cv.z + rv.z, invL, hv.z);
      float v3 = fmaf(cv.w + rv.w, invL, hv.w);
      *(uint32_t*)&attn[row][c0 + g * 4]     = cvtpk(v0, v1);
      *(uint32_t*)&attn[row][c0 + g * 4 + 2] = cvtpk(v2, v3);
    }
  }
  __syncthreads();

  // ---- Phase 3b: out = relu(attn @ Wt^T + bt). 16 waves = 4 rt x 4 cq.
  {
    int rt = w & 3, cq = w >> 2;        // rows rt*16.., cols cq*64..
    f32x4 facc[4];
#pragma unroll
    for (int n = 0; n < 4; ++n) facc[n] = (f32x4){0.f, 0.f, 0.f, 0.f};
    const unsigned short* wwave = WtP + (size_t)(cq * 4) * 512 + (size_t)lane * 8;
#pragma unroll
    for (int kf = 0; kf < 8; ++kf) {
      short8 af = *(const short8*)&attn[rt * 16 + m][kf * 32 + q * 8];
#pragma unroll
      for (int n = 0; n < 4; ++n) {
        short8 bf = *(const short8*)(wwave + ((size_t)kf * 16 + n) * 512);
        facc[n] = __builtin_amdgcn_mfma_f32_16x16x32_bf16(af, bf, facc[n], 0, 0, 0);
      }
    }
#pragma unroll
    for (int n = 0; n < 4; ++n) {
      int col = cq * 64 + n * 16 + m;
      float b = bt[col];
#pragma unroll
      for (int r = 0; r < 4; ++r) {
        size_t row = (size_t)i0 + rt * 16 + q * 4 + r;
        out[row * O_ + col] = fmaxf(facc[n][r] + b, 0.0f);
      }
    }
  }
}

// ---------------------------------------------------------------------------
extern "C" void kernel_launch(void* const* d_in, const int* in_sizes, int n_in,
                              void* d_out, int out_size, void* d_ws, size_t ws_size,
                              hipStream_t stream) {
  const float* Hf  = (const float*)d_in[0];  // [N,D]
  const float* Hc  = (const float*)d_in[1];  // [M,D]
  const float* adj = (const float*)d_in[2];  // [N,M]
  const float* wa  = (const float*)d_in[3];  // [2D]
  const float* ba  = (const float*)d_in[4];  // [1]
  const float* Wt  = (const float*)d_in[5];  // [O,D]
  const float* bt  = (const float*)d_in[6];  // [O]
  float* out = (float*)d_out;

  char* ws = (char*)d_ws;
  float* tv   = (float*)(ws + WS_T);
  float* uv   = (float*)(ws + WS_U);
  float* Rv   = (float*)(ws + WS_R);
  float* Lsum = (float*)(ws + WS_LSUM);
  unsigned short* WtP = (unsigned short*)(ws + WS_WTP);
  unsigned short* BP  = (unsigned short*)(ws + WS_BP);
  unsigned long long* ABM = (unsigned long long*)(ws + WS_ABM);

  hipMemsetAsync(Rv, 0, D_ * sizeof(float), stream);  // atomic target

  prep_kernel<<<5408, 256, 0, stream>>>(Hf, Hc, wa, ba, Wt, tv, uv, BP, WtP, Rv);
  pack_bits_kernel<<<2048, 256, 0, stream>>>(adj, tv, uv, ABM, Lsum);
  mega_kernel<<<256, 1024, 0, stream>>>((const unsigned int*)ABM, BP, tv, uv,
                                        Lsum, Rv, Hf, WtP, bt, out);
}

// Round 4
// 462.449 us; speedup vs baseline: 1.1023x; 1.0176x over previous
//
#include <hip/hip_runtime.h>
#include <hip/hip_bf16.h>
#include <stdint.h>

// Problem constants (fixed by the reference)
#define N_ 16384
#define M_ 4096
#define D_ 256
#define O_ 256

// Workspace layout (bytes), total ~2.3 MB
#define WS_T    0          // float[N]      exp(sf+ba)     64 KB
#define WS_U    65536      // float[M]      exp(sc)        16 KB
#define WS_R    81920      // float[D]      colsum(Hc)      1 KB
#define WS_WTP  98304      // ushort        Wt packed     128 KB
#define WS_BP   229376     // ushort        Hc packed       2 MB

typedef float  f32x4  __attribute__((ext_vector_type(4)));
typedef short  short8 __attribute__((ext_vector_type(8)));

// fp32 -> bf16 (RNE). Inputs are finite so no NaN handling.
__device__ __forceinline__ unsigned short f2bf(float f) {
  uint32_t u = __float_as_uint(f);
  u += 0x7FFFu + ((u >> 16) & 1u);
  return (unsigned short)(u >> 16);
}
// packed pair fp32 -> bf16
__device__ __forceinline__ uint32_t cvtpk(float a, float b) {
  __hip_bfloat162 h = __float22bfloat162_rn(float2{a, b});
  uint32_t u;
  __builtin_memcpy(&u, &h, 4);
  return u;
}

// ---------------------------------------------------------------------------
// Merged prep: blocks [0,4096) rowdot(Hf)->tv, [4096,5120) rowdot(Hc)->uv,
// [5120,5376) hc_pack (BP + colsum->Rv atomics), [5376,5408) wt_pack.
__global__ __launch_bounds__(256) void prep_kernel(
    const float* __restrict__ Hf, const float* __restrict__ Hc,
    const float* __restrict__ wa, const float* __restrict__ ba,
    const float* __restrict__ Wt, float* __restrict__ tv,
    float* __restrict__ uv, unsigned short* __restrict__ BP,
    unsigned short* __restrict__ WtP, float* __restrict__ Rv) {
  __shared__ float tile[64][65];
  __shared__ float red[4][64];
  int b = blockIdx.x;
  int t = threadIdx.x;
  if (b < 5120) {
    // ---- rowdot_exp: per-row dot with weight half, then exp(dot + bias)
    int wv = t >> 6, lane = t & 63;
    const float* X; const float* w; const float* bias; float* outv; int row;
    if (b < 4096) { X = Hf; w = wa;      bias = ba;      outv = tv; row = b * 4 + wv; }
    else          { X = Hc; w = wa + D_; bias = nullptr; outv = uv; row = (b - 4096) * 4 + wv; }
    const float4* x4 = (const float4*)(X + (size_t)row * D_);
    const float4* w4 = (const float4*)w;
    float4 xa = x4[lane], wa4 = w4[lane];
    float s = xa.x * wa4.x + xa.y * wa4.y + xa.z * wa4.z + xa.w * wa4.w;
#pragma unroll
    for (int off = 32; off > 0; off >>= 1) s += __shfl_xor(s, off);
    if (lane == 0) outv[row] = expf(s + (bias ? bias[0] : 0.0f));
  } else if (b < 5376) {
    // ---- hc_pack: Hc [M,D] fp32 -> BP fragment-major bf16 + colsum.
    // BP[((kg*16+cg)*64+lane)*8+j] = bf16(Hc[kg*32+q*8+j][cg*16+m]), lane=q*16+m.
    int bb = b - 5120;
    int bk = bb >> 2;   // 64 tiles along M (k)
    int bc = bb & 3;    // 4 tiles along D (col)
    int k0 = bk * 64, col0 = bc * 64;
    int lane = t & 63, wv = t >> 6;
    int m = lane & 15, q = lane >> 4;
    float colsum = 0.0f;
#pragma unroll
    for (int i = 0; i < 16; ++i) {
      int e = t + 256 * i;
      int kk = e >> 6, cc = e & 63;
      float v = Hc[(size_t)(k0 + kk) * D_ + col0 + cc];
      tile[kk][cc] = v;
      colsum += v;
    }
    red[wv][t & 63] = colsum;
    __syncthreads();
    if (t < 64)
      atomicAdd(&Rv[col0 + t], red[0][t] + red[1][t] + red[2][t] + red[3][t]);
#pragma unroll
    for (int t8 = 0; t8 < 2; ++t8) {
      int tile_id = t8 * 4 + wv;
      int sub = tile_id >> 2, g = tile_id & 3;
      int kgg = bk * 2 + sub;
      int cgg = bc * 4 + g;
      short8 v8;
#pragma unroll
      for (int j = 0; j < 8; ++j)
        v8[j] = (short)f2bf(tile[sub * 32 + q * 8 + j][g * 16 + m]);
      *(short8*)(BP + ((size_t)(kgg * 16 + cgg) * 64 + lane) * 8) = v8;
    }
  } else {
    // ---- wt_pack: Wt [O,D] fp32 -> WtP fragment-major bf16
    int tt = (b - 5376) * 256 + t;    // 0..8191
    int lane = tt & 63, cg = (tt >> 6) & 15, kg = tt >> 10;
    int m = lane & 15, q = lane >> 4;
    const float* src = Wt + (size_t)(cg * 16 + m) * D_ + kg * 32 + q * 8;
    float4 w0 = *(const float4*)src, w1 = *(const float4*)(src + 4);
    short8 v8;
    v8[0] = (short)f2bf(w0.x); v8[1] = (short)f2bf(w0.y);
    v8[2] = (short)f2bf(w0.z); v8[3] = (short)f2bf(w0.w);
    v8[4] = (short)f2bf(w1.x); v8[5] = (short)f2bf(w1.y);
    v8[6] = (short)f2bf(w1.z); v8[7] = (short)f2bf(w1.w);
    *(short8*)(WtP + (size_t)tt * 8) = v8;
  }
}

// ---------------------------------------------------------------------------
// Build a bf16 MFMA A-fragment from 8 adj bits: slot j = bit_j ? (t*u_j - 1) : 0.
// Masking the packed bf16 pair with 0x0000 yields exact +0.0. (R7-proven.)
// Mask build: (int)(bits<<(31-k))>>31 — clang folds to v_bfe_i32 (1-bit
// sign-extend); no __builtin_amdgcn_sbfe (not an exposed clang builtin —
// the R3 compile failure). Merge is the canonical v_bfi pattern.
__device__ __forceinline__ short8 frag_bits(uint32_t bits, float t,
                                            float4 u0, float4 u1) {
  float c[8];
  c[0] = fmaf(t, u0.x, -1.0f); c[1] = fmaf(t, u0.y, -1.0f);
  c[2] = fmaf(t, u0.z, -1.0f); c[3] = fmaf(t, u0.w, -1.0f);
  c[4] = fmaf(t, u1.x, -1.0f); c[5] = fmaf(t, u1.y, -1.0f);
  c[6] = fmaf(t, u1.z, -1.0f); c[7] = fmaf(t, u1.w, -1.0f);
  union { short8 s; uint32_t u[4]; } r;
#pragma unroll
  for (int p = 0; p < 4; ++p) {
    uint32_t mlo = (uint32_t)((int32_t)(bits << (31 - 2 * p)) >> 31);
    uint32_t mhi = (uint32_t)((int32_t)(bits << (30 - 2 * p)) >> 31);
    r.u[p] = cvtpk(c[2 * p], c[2 * p + 1]) &
             ((mlo & 0x0000FFFFu) | (mhi & 0xFFFF0000u));   // v_bfi
  }
  return r.s;
}

// ---------------------------------------------------------------------------
// Mega kernel v2: pack_bits fused as prologue + masked GEMM + fused epilogue.
// Prologue: each block reads adj for its 64 rows (1 MB) with the proven
//   2-rows/wave streaming pattern (16 waves x 2 KB in flight = 32 KB/CU),
//   ballot-packs bits straight into LDS bt2, computes Lsum into LDS.
//   Replaces the separate pack_bits dispatch + 16 MB ABM round-trip.
// Phase 1 (K-loop): 16 waves (4 colq x 4 ksub); each wave 4 row-tiles x
//   4 col-groups x 1024-K quarter. B prepacked, depth-1 register prefetch,
//   barrier-free. frag_bits now BFE/BFI idioms (~35% VALU cut).
// Phase 2: sequential ksub-plane reduction into fp32 LDS Cred (exact).
// Phase 3: attn = (Cred+R)/(Lsum+M) + Hf -> bf16 LDS (aliased over dead
//   bit-table), then attn @ Wt^T + bt, ReLU -> out.
// LDS: bt2 33 KB | u 16 KB | Cred 64 KB | Lsum 256 B = 115.2 KB -> 1 blk/CU.
__global__ __launch_bounds__(1024, 4) void mega_kernel(
    const float* __restrict__ adj, const unsigned short* __restrict__ BP,
    const float* __restrict__ tv, const float* __restrict__ uv,
    const float* __restrict__ Rv, const float* __restrict__ Hf,
    const unsigned short* __restrict__ WtP, const float* __restrict__ bt,
    float* __restrict__ out) {
  __shared__ __align__(16) char smem[115200];
  unsigned int (*bt2)[129] = (unsigned int (*)[129])(smem);           // 33024 B
  float* u_lds = (float*)(smem + 33024);                              // 16384 B
  float (*Cred)[256] = (float (*)[256])(smem + 49408);                // 65536 B
  float* Lsum_lds = (float*)(smem + 114944);                          // 256 B
  unsigned short (*attn)[264] = (unsigned short (*)[264])(smem);      // 33792 B (aliases bt2+u, dead by then)

  int tid = threadIdx.x;
  int w = tid >> 6, lane = tid & 63;
  int q = lane >> 4, m = lane & 15;
  int colq = w >> 2, ksub = w & 3;
  int i0 = blockIdx.x * 64;

  for (int i = tid; i < M_; i += 1024) u_lds[i] = uv[i];
  __syncthreads();  // u ready (prologue needs it for Lsum fmas)

  // ---- Prologue: adj -> bits in LDS + Lsum. Wave w owns rows w*4..w*4+3,
  // processed 2-at-a-time with depth-1 prefetch (pack_bits-proven body).
#pragma unroll 1
  for (int pass = 0; pass < 2; ++pass) {
    int r0 = w * 4 + pass * 2;
    const float* arA = adj + ((size_t)i0 + r0) * M_;
    const float* arB = arA + M_;
    float suA = 0.f, scA = 0.f, suB = 0.f, scB = 0.f;
    float a0 = arA[lane], a1 = arA[64 + lane], a2 = arA[128 + lane], a3 = arA[192 + lane];
    float b0 = arB[lane], b1 = arB[64 + lane], b2 = arB[128 + lane], b3 = arB[192 + lane];
#pragma unroll 1
    for (int i = 0; i < 16; ++i) {
      int k0 = i * 256;
      int k1 = (i + 1 < 16) ? k0 + 256 : 0;     // wrap: harmless reload
      float na0 = arA[k1 + lane],       na1 = arA[k1 + 64 + lane];
      float na2 = arA[k1 + 128 + lane], na3 = arA[k1 + 192 + lane];
      float nb0 = arB[k1 + lane],       nb1 = arB[k1 + 64 + lane];
      float nb2 = arB[k1 + 128 + lane], nb3 = arB[k1 + 192 + lane];

      unsigned long long wA0 = __ballot(a0 != 0.0f), wA1 = __ballot(a1 != 0.0f);
      unsigned long long wA2 = __ballot(a2 != 0.0f), wA3 = __ballot(a3 != 0.0f);
      unsigned long long wB0 = __ballot(b0 != 0.0f), wB1 = __ballot(b1 != 0.0f);
      unsigned long long wB2 = __ballot(b2 != 0.0f), wB3 = __ballot(b3 != 0.0f);
      suA = fmaf(a0, u_lds[k0 + lane], suA);
      suA = fmaf(a1, u_lds[k0 + 64 + lane], suA);
      suA = fmaf(a2, u_lds[k0 + 128 + lane], suA);
      suA = fmaf(a3, u_lds[k0 + 192 + lane], suA);
      scA += (a0 + a1) + (a2 + a3);
      suB = fmaf(b0, u_lds[k0 + lane], suB);
      suB = fmaf(b1, u_lds[k0 + 64 + lane], suB);
      suB = fmaf(b2, u_lds[k0 + 128 + lane], suB);
      suB = fmaf(b3, u_lds[k0 + 192 + lane], suB);
      scB += (b0 + b1) + (b2 + b3);
      if (lane < 16) {
        int rowsel = lane >> 3;                 // 0 = row A, 1 = row B
        int c = (lane >> 1) & 3, hi = lane & 1;
        unsigned long long v = rowsel ? (c == 0 ? wB0 : c == 1 ? wB1 : c == 2 ? wB2 : wB3)
                                      : (c == 0 ? wA0 : c == 1 ? wA1 : c == 2 ? wA2 : wA3);
        bt2[r0 + rowsel][i * 8 + c * 2 + hi] =
            hi ? (unsigned int)(v >> 32) : (unsigned int)v;
      }
      a0 = na0; a1 = na1; a2 = na2; a3 = na3;
      b0 = nb0; b1 = nb1; b2 = nb2; b3 = nb3;
    }
#pragma unroll
    for (int off = 32; off > 0; off >>= 1) {
      suA += __shfl_xor(suA, off); scA += __shfl_xor(scA, off);
      suB += __shfl_xor(suB, off); scB += __shfl_xor(scB, off);
    }
    if (lane == 0) {
      Lsum_lds[r0]     = tv[i0 + r0] * suA - scA;
      Lsum_lds[r0 + 1] = tv[i0 + r0 + 1] * suB - scB;
    }
  }

  // B base + first-kstep prefetch (no LDS dep; overlaps the barrier)
  const unsigned short* bbase = BP + (size_t)(colq * 4) * 512 + (size_t)lane * 8;
  int kg0 = ksub * 32;
  short8 curB[4];
#pragma unroll
  for (int n = 0; n < 4; ++n)
    curB[n] = *(const short8*)(bbase + ((size_t)kg0 * 16 + n) * 512);
  float t0 = tv[i0 + m], t1 = tv[i0 + 16 + m];
  float t2 = tv[i0 + 32 + m], t3 = tv[i0 + 48 + m];

  f32x4 acc[4][4];
#pragma unroll
  for (int s = 0; s < 4; ++s)
#pragma unroll
    for (int n = 0; n < 4; ++n) acc[s][n] = (f32x4){0.f, 0.f, 0.f, 0.f};

  __syncthreads();  // bits + Lsum ready

  for (int it = 0; it < 32; ++it) {
    int kg = kg0 + it;
    int kn = (it + 1 < 32) ? kg + 1 : kg0;   // wrap: harmless reload
    short8 nB[4];
#pragma unroll
    for (int n = 0; n < 4; ++n)
      nB[n] = *(const short8*)(bbase + ((size_t)kn * 16 + n) * 512);

    float4 u0 = *(const float4*)&u_lds[kg * 32 + q * 8];
    float4 u1 = *(const float4*)&u_lds[kg * 32 + q * 8 + 4];
    uint32_t b0 = bt2[m][kg],      b1 = bt2[16 + m][kg];
    uint32_t b2 = bt2[32 + m][kg], b3 = bt2[48 + m][kg];
    int sh = q * 8;
    short8 af0 = frag_bits((b0 >> sh) & 0xffu, t0, u0, u1);
    short8 af1 = frag_bits((b1 >> sh) & 0xffu, t1, u0, u1);
    short8 af2 = frag_bits((b2 >> sh) & 0xffu, t2, u0, u1);
    short8 af3 = frag_bits((b3 >> sh) & 0xffu, t3, u0, u1);
#pragma unroll
    for (int n = 0; n < 4; ++n) {
      acc[0][n] = __builtin_amdgcn_mfma_f32_16x16x32_bf16(af0, curB[n], acc[0][n], 0, 0, 0);
      acc[1][n] = __builtin_amdgcn_mfma_f32_16x16x32_bf16(af1, curB[n], acc[1][n], 0, 0, 0);
      acc[2][n] = __builtin_amdgcn_mfma_f32_16x16x32_bf16(af2, curB[n], acc[2][n], 0, 0, 0);
      acc[3][n] = __builtin_amdgcn_mfma_f32_16x16x32_bf16(af3, curB[n], acc[3][n], 0, 0, 0);
    }
#pragma unroll
    for (int n = 0; n < 4; ++n) curB[n] = nB[n];
  }

  // ---- Phase 2: sequential ksub-plane reduction into fp32 Cred (exact)
#pragma unroll
  for (int s4 = 0; s4 < 4; ++s4) {
    if (ksub == s4) {
#pragma unroll
      for (int s = 0; s < 4; ++s)
#pragma unroll
        for (int n = 0; n < 4; ++n) {
          int col = colq * 64 + n * 16 + m;
#pragma unroll
          for (int r = 0; r < 4; ++r) {
            int rl = s * 16 + q * 4 + r;     // C/D: row=(lane>>4)*4+reg
            if (s4 == 0) Cred[rl][col] = acc[s][n][r];
            else         Cred[rl][col] += acc[s][n][r];
          }
        }
    }
    __syncthreads();
  }

  // ---- Phase 3a: attn = (Cred + R)/(Lsum + M) + Hf -> bf16 LDS
  {
    int row = tid >> 4;                 // 0..63, 16 threads per row
    int c0 = (tid & 15) * 16;           // 16 consecutive cols per thread
    size_t grow = (size_t)i0 + row;
    float invL = 1.0f / (Lsum_lds[row] + (float)M_);
    const float* hfp = Hf + grow * D_ + c0;
    const float* rvp = Rv + c0;
    const float* crp = &Cred[row][c0];
#pragma unroll
    for (int g = 0; g < 4; ++g) {
      float4 cv = *(const float4*)(crp + g * 4);
      float4 rv = *(const float4*)(rvp + g * 4);
      float4 hv = *(const float4*)(hfp + g * 4);
      float v0 = fmaf(cv.x + rv.x, invL, hv.x);
      float v1 = fmaf(cv.y + rv.y, invL, hv.y);
      float v2 = fmaf(cv.z + rv.z, invL, hv.z);
      float v3 = fmaf(cv.w + rv.w, invL, hv.w);
      *(uint32_t*)&attn[row][c0 + g * 4]     = cvtpk(v0, v1);
      *(uint32_t*)&attn[row][c0 + g * 4 + 2] = cvtpk(v2, v3);
    }
  }
  __syncthreads();

  // ---- Phase 3b: out = relu(attn @ Wt^T + bt). 16 waves = 4 rt x 4 cq.
  {
    int rt = w & 3, cq = w >> 2;        // rows rt*16.., cols cq*64..
    f32x4 facc[4];
#pragma unroll
    for (int n = 0; n < 4; ++n) facc[n] = (f32x4){0.f, 0.f, 0.f, 0.f};
    const unsigned short* wwave = WtP + (size_t)(cq * 4) * 512 + (size_t)lane * 8;
#pragma unroll
    for (int kf = 0; kf < 8; ++kf) {
      short8 af = *(const short8*)&attn[rt * 16 + m][kf * 32 + q * 8];
#pragma unroll
      for (int n = 0; n < 4; ++n) {
        short8 bf = *(const short8*)(wwave + ((size_t)kf * 16 + n) * 512);
        facc[n] = __builtin_amdgcn_mfma_f32_16x16x32_bf16(af, bf, facc[n], 0, 0, 0);
      }
    }
#pragma unroll
    for (int n = 0; n < 4; ++n) {
      int col = cq * 64 + n * 16 + m;
      float b = bt[col];
#pragma unroll
      for (int r = 0; r < 4; ++r) {
        size_t row = (size_t)i0 + rt * 16 + q * 4 + r;
        out[row * O_ + col] = fmaxf(facc[n][r] + b, 0.0f);
      }
    }
  }
}

// ---------------------------------------------------------------------------
extern "C" void kernel_launch(void* const* d_in, const int* in_sizes, int n_in,
                              void* d_out, int out_size, void* d_ws, size_t ws_size,
                              hipStream_t stream) {
  const float* Hf  = (const float*)d_in[0];  // [N,D]
  const float* Hc  = (const float*)d_in[1];  // [M,D]
  const float* adj = (const float*)d_in[2];  // [N,M]
  const float* wa  = (const float*)d_in[3];  // [2D]
  const float* ba  = (const float*)d_in[4];  // [1]
  const float* Wt  = (const float*)d_in[5];  // [O,D]
  const float* bt  = (const float*)d_in[6];  // [O]
  float* out = (float*)d_out;

  char* ws = (char*)d_ws;
  float* tv   = (float*)(ws + WS_T);
  float* uv   = (float*)(ws + WS_U);
  float* Rv   = (float*)(ws + WS_R);
  unsigned short* WtP = (unsigned short*)(ws + WS_WTP);
  unsigned short* BP  = (unsigned short*)(ws + WS_BP);

  hipMemsetAsync(Rv, 0, D_ * sizeof(float), stream);  // atomic target

  prep_kernel<<<5408, 256, 0, stream>>>(Hf, Hc, wa, ba, Wt, tv, uv, BP, WtP, Rv);
  mega_kernel<<<256, 1024, 0, stream>>>(adj, BP, tv, uv, Rv, Hf, WtP, bt, out);
}

// Round 5
// 440.840 us; speedup vs baseline: 1.1563x; 1.0490x over previous
//
#include <hip/hip_runtime.h>
#include <hip/hip_fp16.h>
#include <stdint.h>

// Problem constants (fixed by the reference)
#define N_ 16384
#define M_ 4096
#define D_ 256
#define O_ 256

// Workspace layout (bytes), total ~2.3 MB
#define WS_T    0          // float[N]      exp(sf+ba)     64 KB
#define WS_U    65536      // float[M]      exp(sc)        16 KB
#define WS_R    81920      // float[D]      colsum(Hc)      1 KB
#define WS_WTP  98304      // ushort        Wt packed f16 128 KB
#define WS_BP   229376     // ushort        Hc packed f16   2 MB

typedef float  f32x4  __attribute__((ext_vector_type(4)));
typedef _Float16 half8 __attribute__((ext_vector_type(8)));

// fp32 -> f16 bits (RNE)
__device__ __forceinline__ unsigned short f2h(float f) {
  __half h = __float2half(f);
  unsigned short u;
  __builtin_memcpy(&u, &h, 2);
  return u;
}
// pack two fp32 -> f16x2 bits
__device__ __forceinline__ uint32_t hpack(float a, float b) {
  __half2 h = __floats2half2_rn(a, b);
  uint32_t u;
  __builtin_memcpy(&u, &h, 4);
  return u;
}

// ---------------------------------------------------------------------------
// Merged prep: blocks [0,4096) rowdot(Hf)->tv, [4096,5120) rowdot(Hc)->uv,
// [5120,5376) hc_pack (BP f16 + colsum->Rv atomics), [5376,5408) wt_pack f16.
__global__ __launch_bounds__(256) void prep_kernel(
    const float* __restrict__ Hf, const float* __restrict__ Hc,
    const float* __restrict__ wa, const float* __restrict__ ba,
    const float* __restrict__ Wt, float* __restrict__ tv,
    float* __restrict__ uv, unsigned short* __restrict__ BP,
    unsigned short* __restrict__ WtP, float* __restrict__ Rv) {
  __shared__ float tile[64][65];
  __shared__ float red[4][64];
  int b = blockIdx.x;
  int t = threadIdx.x;
  if (b < 5120) {
    // ---- rowdot_exp: per-row dot with weight half, then exp(dot + bias)
    int wv = t >> 6, lane = t & 63;
    const float* X; const float* w; const float* bias; float* outv; int row;
    if (b < 4096) { X = Hf; w = wa;      bias = ba;      outv = tv; row = b * 4 + wv; }
    else          { X = Hc; w = wa + D_; bias = nullptr; outv = uv; row = (b - 4096) * 4 + wv; }
    const float4* x4 = (const float4*)(X + (size_t)row * D_);
    const float4* w4 = (const float4*)w;
    float4 xa = x4[lane], wa4 = w4[lane];
    float s = xa.x * wa4.x + xa.y * wa4.y + xa.z * wa4.z + xa.w * wa4.w;
#pragma unroll
    for (int off = 32; off > 0; off >>= 1) s += __shfl_xor(s, off);
    if (lane == 0) outv[row] = expf(s + (bias ? bias[0] : 0.0f));
  } else if (b < 5376) {
    // ---- hc_pack: Hc [M,D] fp32 -> BP fragment-major f16 + colsum.
    // BP[((kg*16+cg)*64+lane)*8+j] = f16(Hc[kg*32+q*8+j][cg*16+m]), lane=q*16+m.
    int bb = b - 5120;
    int bk = bb >> 2;   // 64 tiles along M (k)
    int bc = bb & 3;    // 4 tiles along D (col)
    int k0 = bk * 64, col0 = bc * 64;
    int lane = t & 63, wv = t >> 6;
    int m = lane & 15, q = lane >> 4;
    float colsum = 0.0f;
#pragma unroll
    for (int i = 0; i < 16; ++i) {
      int e = t + 256 * i;
      int kk = e >> 6, cc = e & 63;
      float v = Hc[(size_t)(k0 + kk) * D_ + col0 + cc];
      tile[kk][cc] = v;
      colsum += v;
    }
    red[wv][t & 63] = colsum;
    __syncthreads();
    if (t < 64)
      atomicAdd(&Rv[col0 + t], red[0][t] + red[1][t] + red[2][t] + red[3][t]);
#pragma unroll
    for (int t8 = 0; t8 < 2; ++t8) {
      int tile_id = t8 * 4 + wv;
      int sub = tile_id >> 2, g = tile_id & 3;
      int kgg = bk * 2 + sub;
      int cgg = bc * 4 + g;
      unsigned short v8[8];
#pragma unroll
      for (int j = 0; j < 8; ++j)
        v8[j] = f2h(tile[sub * 32 + q * 8 + j][g * 16 + m]);
      *(uint4*)(BP + ((size_t)(kgg * 16 + cgg) * 64 + lane) * 8) = *(uint4*)v8;
    }
  } else {
    // ---- wt_pack: Wt [O,D] fp32 -> WtP fragment-major f16
    int tt = (b - 5376) * 256 + t;    // 0..8191
    int lane = tt & 63, cg = (tt >> 6) & 15, kg = tt >> 10;
    int m = lane & 15, q = lane >> 4;
    const float* src = Wt + (size_t)(cg * 16 + m) * D_ + kg * 32 + q * 8;
    float4 w0 = *(const float4*)src, w1 = *(const float4*)(src + 4);
    unsigned short v8[8];
    v8[0] = f2h(w0.x); v8[1] = f2h(w0.y); v8[2] = f2h(w0.z); v8[3] = f2h(w0.w);
    v8[4] = f2h(w1.x); v8[5] = f2h(w1.y); v8[6] = f2h(w1.z); v8[7] = f2h(w1.w);
    *(uint4*)(WtP + (size_t)tt * 8) = *(uint4*)v8;
  }
}

// ---------------------------------------------------------------------------
// Build an f16 MFMA A-fragment from 8 adj bits: slot j = bit_j ? (t*u_j - 1) : 0.
// One v_pk_fma_f16 per pair (t,u pre-packed half2); mask via BFE/BFI idioms.
// Masking with 0x0000 yields exact +0.0.
__device__ __forceinline__ half8 frag_f16(uint32_t bits, __half2 th,
                                          const __half2* up, __half2 mone) {
  union { half8 h; uint32_t u[4]; } r;
#pragma unroll
  for (int p = 0; p < 4; ++p) {
    __half2 v = __hfma2(th, up[p], mone);
    uint32_t c;
    __builtin_memcpy(&c, &v, 4);
    uint32_t mlo = (uint32_t)((int32_t)(bits << (31 - 2 * p)) >> 31);
    uint32_t mhi = (uint32_t)((int32_t)(bits << (30 - 2 * p)) >> 31);
    r.u[p] = c & ((mlo & 0x0000FFFFu) | (mhi & 0xFFFF0000u));   // v_bfi
  }
  return r.h;
}

// ---------------------------------------------------------------------------
// Mega kernel v3: fused prologue + f16 masked GEMM + fused epilogue.
// K-loop per kstep/wave: 4x(4 pk_fma + 16 mask ops) + 1 ds_b128 (u half2)
// + 0.5 ds_b64 (bits, unroll-2) + 4 global b128 (B dbuf) + 16 MFMA —
// ~110 insts vs R4's measured-implied ~550 (AGPR-shuffle + cvt overhead).
// Explicit A/B double-buffer (no rotation movs); per-row frag build keeps
// non-acc live set ~64 VGPR to match the forced 64 VGPR + 64 AGPR split.
// LDS: bt2[64][130] 33.3K | u_f32 16K | u_h2 8K | Cred 64K | Lsum .25K
//    = 123.6 KB -> 1 block/CU.
__global__ __launch_bounds__(1024, 4) void mega_kernel(
    const float* __restrict__ adj, const unsigned short* __restrict__ BP,
    const float* __restrict__ tv, const float* __restrict__ uv,
    const float* __restrict__ Rv, const float* __restrict__ Hf,
    const unsigned short* __restrict__ WtP, const float* __restrict__ bt,
    float* __restrict__ out) {
  __shared__ __align__(16) char smem[123648];
  unsigned int (*bt2)[130] = (unsigned int (*)[130])(smem);           // 33280 B
  float* u_lds = (float*)(smem + 33280);                              // 16384 B
  uint32_t* u_h2 = (uint32_t*)(smem + 49664);                         //  8192 B
  float (*Cred)[256] = (float (*)[256])(smem + 57856);                // 65536 B
  float* Lsum_lds = (float*)(smem + 123392);                          //   256 B
  unsigned short (*attn)[264] = (unsigned short (*)[264])(smem);      // 33792 B (aliases bt2+u, dead by then)

  int tid = threadIdx.x;
  int w = tid >> 6, lane = tid & 63;
  int q = lane >> 4, m = lane & 15;
  int colq = w >> 2, ksub = w & 3;
  int i0 = blockIdx.x * 64;

  // u: f32 copy (prologue) + packed half2 copy (K-loop)
  for (int i = tid; i < M_ / 2; i += 1024) {
    float2 u2 = *(const float2*)(uv + 2 * i);
    u_lds[2 * i] = u2.x; u_lds[2 * i + 1] = u2.y;
    u_h2[i] = hpack(u2.x, u2.y);
  }
  __syncthreads();  // u ready (prologue needs it for Lsum fmas)

  // ---- Prologue: adj -> bits in LDS + Lsum. Wave w owns rows w*4..w*4+3,
  // processed 2-at-a-time with depth-1 prefetch (pack_bits-proven body).
#pragma unroll 1
  for (int pass = 0; pass < 2; ++pass) {
    int r0 = w * 4 + pass * 2;
    const float* arA = adj + ((size_t)i0 + r0) * M_;
    const float* arB = arA + M_;
    float suA = 0.f, scA = 0.f, suB = 0.f, scB = 0.f;
    float a0 = arA[lane], a1 = arA[64 + lane], a2 = arA[128 + lane], a3 = arA[192 + lane];
    float b0 = arB[lane], b1 = arB[64 + lane], b2 = arB[128 + lane], b3 = arB[192 + lane];
#pragma unroll 1
    for (int i = 0; i < 16; ++i) {
      int k0 = i * 256;
      int k1 = (i + 1 < 16) ? k0 + 256 : 0;     // wrap: harmless reload
      float na0 = arA[k1 + lane],       na1 = arA[k1 + 64 + lane];
      float na2 = arA[k1 + 128 + lane], na3 = arA[k1 + 192 + lane];
      float nb0 = arB[k1 + lane],       nb1 = arB[k1 + 64 + lane];
      float nb2 = arB[k1 + 128 + lane], nb3 = arB[k1 + 192 + lane];

      unsigned long long wA0 = __ballot(a0 != 0.0f), wA1 = __ballot(a1 != 0.0f);
      unsigned long long wA2 = __ballot(a2 != 0.0f), wA3 = __ballot(a3 != 0.0f);
      unsigned long long wB0 = __ballot(b0 != 0.0f), wB1 = __ballot(b1 != 0.0f);
      unsigned long long wB2 = __ballot(b2 != 0.0f), wB3 = __ballot(b3 != 0.0f);
      suA = fmaf(a0, u_lds[k0 + lane], suA);
      suA = fmaf(a1, u_lds[k0 + 64 + lane], suA);
      suA = fmaf(a2, u_lds[k0 + 128 + lane], suA);
      suA = fmaf(a3, u_lds[k0 + 192 + lane], suA);
      scA += (a0 + a1) + (a2 + a3);
      suB = fmaf(b0, u_lds[k0 + lane], suB);
      suB = fmaf(b1, u_lds[k0 + 64 + lane], suB);
      suB = fmaf(b2, u_lds[k0 + 128 + lane], suB);
      suB = fmaf(b3, u_lds[k0 + 192 + lane], suB);
      scB += (b0 + b1) + (b2 + b3);
      if (lane < 16) {
        int rowsel = lane >> 3;                 // 0 = row A, 1 = row B
        int c = (lane >> 1) & 3, hi = lane & 1;
        unsigned long long v = rowsel ? (c == 0 ? wB0 : c == 1 ? wB1 : c == 2 ? wB2 : wB3)
                                      : (c == 0 ? wA0 : c == 1 ? wA1 : c == 2 ? wA2 : wA3);
        bt2[r0 + rowsel][i * 8 + c * 2 + hi] =
            hi ? (unsigned int)(v >> 32) : (unsigned int)v;
      }
      a0 = na0; a1 = na1; a2 = na2; a3 = na3;
      b0 = nb0; b1 = nb1; b2 = nb2; b3 = nb3;
    }
#pragma unroll
    for (int off = 32; off > 0; off >>= 1) {
      suA += __shfl_xor(suA, off); scA += __shfl_xor(scA, off);
      suB += __shfl_xor(suB, off); scB += __shfl_xor(scB, off);
    }
    if (lane == 0) {
      Lsum_lds[r0]     = tv[i0 + r0] * suA - scA;
      Lsum_lds[r0 + 1] = tv[i0 + r0 + 1] * suB - scB;
    }
  }

  // B base + first-kstep prefetch (no LDS dep; overlaps the barrier)
  const unsigned short* bbase = BP + (size_t)(colq * 4) * 512 + (size_t)lane * 8;
  int kg0 = ksub * 32;
  half8 bufA[4], bufB[4];
#pragma unroll
  for (int n = 0; n < 4; ++n)
    bufA[n] = *(const half8*)(bbase + ((size_t)kg0 * 16 + n) * 512);

  __half2 th0 = __float2half2_rn(tv[i0 + m]);
  __half2 th1 = __float2half2_rn(tv[i0 + 16 + m]);
  __half2 th2 = __float2half2_rn(tv[i0 + 32 + m]);
  __half2 th3 = __float2half2_rn(tv[i0 + 48 + m]);
  const __half2 mone = __float2half2_rn(-1.0f);

  f32x4 acc[4][4];
#pragma unroll
  for (int s = 0; s < 4; ++s)
#pragma unroll
    for (int n = 0; n < 4; ++n) acc[s][n] = (f32x4){0.f, 0.f, 0.f, 0.f};

  __syncthreads();  // bits + Lsum ready

#pragma unroll 1
  for (int it2 = 0; it2 < 16; ++it2) {
    int kg = kg0 + it2 * 2;
    // bits for 2 ksteps x 4 row-tiles: one ds_read_b64 each (conflict-free)
    uint2 W0 = *(const uint2*)&bt2[m][kg];
    uint2 W1 = *(const uint2*)&bt2[16 + m][kg];
    uint2 W2 = *(const uint2*)&bt2[32 + m][kg];
    uint2 W3 = *(const uint2*)&bt2[48 + m][kg];
    int sh = q * 8;

    // ---- kstep kg (bufA); prefetch kg+1 into bufB
#pragma unroll
    for (int n = 0; n < 4; ++n)
      bufB[n] = *(const half8*)(bbase + ((size_t)(kg + 1) * 16 + n) * 512);
    {
      uint4 uu = *(const uint4*)&u_h2[kg * 16 + q * 4];
      __half2 up[4];
      __builtin_memcpy(up, &uu, 16);
      half8 af;
      af = frag_f16((W0.x >> sh) & 0xffu, th0, up, mone);
#pragma unroll
      for (int n = 0; n < 4; ++n)
        acc[0][n] = __builtin_amdgcn_mfma_f32_16x16x32_f16(af, bufA[n], acc[0][n], 0, 0, 0);
      af = frag_f16((W1.x >> sh) & 0xffu, th1, up, mone);
#pragma unroll
      for (int n = 0; n < 4; ++n)
        acc[1][n] = __builtin_amdgcn_mfma_f32_16x16x32_f16(af, bufA[n], acc[1][n], 0, 0, 0);
      af = frag_f16((W2.x >> sh) & 0xffu, th2, up, mone);
#pragma unroll
      for (int n = 0; n < 4; ++n)
        acc[2][n] = __builtin_amdgcn_mfma_f32_16x16x32_f16(af, bufA[n], acc[2][n], 0, 0, 0);
      af = frag_f16((W3.x >> sh) & 0xffu, th3, up, mone);
#pragma unroll
      for (int n = 0; n < 4; ++n)
        acc[3][n] = __builtin_amdgcn_mfma_f32_16x16x32_f16(af, bufA[n], acc[3][n], 0, 0, 0);
    }

    // ---- kstep kg+1 (bufB); prefetch kg+2 into bufA (wrap: harmless reload)
    int kn = (it2 + 1 < 16) ? kg + 2 : kg0;
#pragma unroll
    for (int n = 0; n < 4; ++n)
      bufA[n] = *(const half8*)(bbase + ((size_t)kn * 16 + n) * 512);
    {
      uint4 uu = *(const uint4*)&u_h2[(kg + 1) * 16 + q * 4];
      __half2 up[4];
      __builtin_memcpy(up, &uu, 16);
      half8 af;
      af = frag_f16((W0.y >> sh) & 0xffu, th0, up, mone);
#pragma unroll
      for (int n = 0; n < 4; ++n)
        acc[0][n] = __builtin_amdgcn_mfma_f32_16x16x32_f16(af, bufB[n], acc[0][n], 0, 0, 0);
      af = frag_f16((W1.y >> sh) & 0xffu, th1, up, mone);
#pragma unroll
      for (int n = 0; n < 4; ++n)
        acc[1][n] = __builtin_amdgcn_mfma_f32_16x16x32_f16(af, bufB[n], acc[1][n], 0, 0, 0);
      af = frag_f16((W2.y >> sh) & 0xffu, th2, up, mone);
#pragma unroll
      for (int n = 0; n < 4; ++n)
        acc[2][n] = __builtin_amdgcn_mfma_f32_16x16x32_f16(af, bufB[n], acc[2][n], 0, 0, 0);
      af = frag_f16((W3.y >> sh) & 0xffu, th3, up, mone);
#pragma unroll
      for (int n = 0; n < 4; ++n)
        acc[3][n] = __builtin_amdgcn_mfma_f32_16x16x32_f16(af, bufB[n], acc[3][n], 0, 0, 0);
    }
  }

  // ---- Phase 2: sequential ksub-plane reduction into fp32 Cred (exact)
#pragma unroll
  for (int s4 = 0; s4 < 4; ++s4) {
    if (ksub == s4) {
#pragma unroll
      for (int s = 0; s < 4; ++s)
#pragma unroll
        for (int n = 0; n < 4; ++n) {
          int col = colq * 64 + n * 16 + m;
#pragma unroll
          for (int r = 0; r < 4; ++r) {
            int rl = s * 16 + q * 4 + r;     // C/D: row=(lane>>4)*4+reg
            if (s4 == 0) Cred[rl][col] = acc[s][n][r];
            else         Cred[rl][col] += acc[s][n][r];
          }
        }
    }
    __syncthreads();
  }

  // ---- Phase 3a: attn = (Cred + R)/(Lsum + M) + Hf -> f16 LDS
  {
    int row = tid >> 4;                 // 0..63, 16 threads per row
    int c0 = (tid & 15) * 16;           // 16 consecutive cols per thread
    size_t grow = (size_t)i0 + row;
    float invL = 1.0f / (Lsum_lds[row] + (float)M_);
    const float* hfp = Hf + grow * D_ + c0;
    const float* rvp = Rv + c0;
    const float* crp = &Cred[row][c0];
#pragma unroll
    for (int g = 0; g < 4; ++g) {
      float4 cv = *(const float4*)(crp + g * 4);
      float4 rv = *(const float4*)(rvp + g * 4);
      float4 hv = *(const float4*)(hfp + g * 4);
      float v0 = fmaf(cv.x + rv.x, invL, hv.x);
      float v1 = fmaf(cv.y + rv.y, invL, hv.y);
      float v2 = fmaf(cv.z + rv.z, invL, hv.z);
      float v3 = fmaf(cv.w + rv.w, invL, hv.w);
      *(uint32_t*)&attn[row][c0 + g * 4]     = hpack(v0, v1);
      *(uint32_t*)&attn[row][c0 + g * 4 + 2] = hpack(v2, v3);
    }
  }
  __syncthreads();

  // ---- Phase 3b: out = relu(attn @ Wt^T + bt). 16 waves = 4 rt x 4 cq.
  {
    int rt = w & 3, cq = w >> 2;        // rows rt*16.., cols cq*64..
    f32x4 facc[4];
#pragma unroll
    for (int n = 0; n < 4; ++n) facc[n] = (f32x4){0.f, 0.f, 0.f, 0.f};
    const unsigned short* wwave = WtP + (size_t)(cq * 4) * 512 + (size_t)lane * 8;
#pragma unroll
    for (int kf = 0; kf < 8; ++kf) {
      half8 af = *(const half8*)&attn[rt * 16 + m][kf * 32 + q * 8];
#pragma unroll
      for (int n = 0; n < 4; ++n) {
        half8 bf = *(const half8*)(wwave + ((size_t)kf * 16 + n) * 512);
        facc[n] = __builtin_amdgcn_mfma_f32_16x16x32_f16(af, bf, facc[n], 0, 0, 0);
      }
    }
#pragma unroll
    for (int n = 0; n < 4; ++n) {
      int col = cq * 64 + n * 16 + m;
      float b = bt[col];
#pragma unroll
      for (int r = 0; r < 4; ++r) {
        size_t row = (size_t)i0 + rt * 16 + q * 4 + r;
        out[row * O_ + col] = fmaxf(facc[n][r] + b, 0.0f);
      }
    }
  }
}

// ---------------------------------------------------------------------------
extern "C" void kernel_launch(void* const* d_in, const int* in_sizes, int n_in,
                              void* d_out, int out_size, void* d_ws, size_t ws_size,
                              hipStream_t stream) {
  const float* Hf  = (const float*)d_in[0];  // [N,D]
  const float* Hc  = (const float*)d_in[1];  // [M,D]
  const float* adj = (const float*)d_in[2];  // [N,M]
  const float* wa  = (const float*)d_in[3];  // [2D]
  const float* ba  = (const float*)d_in[4];  // [1]
  const float* Wt  = (const float*)d_in[5];  // [O,D]
  const float* bt  = (const float*)d_in[6];  // [O]
  float* out = (float*)d_out;

  char* ws = (char*)d_ws;
  float* tv   = (float*)(ws + WS_T);
  float* uv   = (float*)(ws + WS_U);
  float* Rv   = (float*)(ws + WS_R);
  unsigned short* WtP = (unsigned short*)(ws + WS_WTP);
  unsigned short* BP  = (unsigned short*)(ws + WS_BP);

  hipMemsetAsync(Rv, 0, D_ * sizeof(float), stream);  // atomic target

  prep_kernel<<<5408, 256, 0, stream>>>(Hf, Hc, wa, ba, Wt, tv, uv, BP, WtP, Rv);
  mega_kernel<<<256, 1024, 0, stream>>>(adj, BP, tv, uv, Rv, Hf, WtP, bt, out);
}